// Round 16
// baseline (574.087 us; speedup 1.0000x reference)
//
#include <hip/hip_runtime.h>
#include <cmath>

static constexpr int NN  = 50000;   // nodes
static constexpr int NE  = 800000;  // edges
static constexpr int HID = 64;
static constexpr int BB  = 64;      // batch
static constexpr int TT  = 200;     // seq len
static constexpr int LH  = 128;     // lstm hidden
static constexpr int G4  = 512;     // 4*LH
static constexpr int NTILES = NE / 64;   // 12500

static constexpr int SCB = 125;     // scan blocks
static constexpr int SCH = 400;     // elems per scan block (125*400 = 50000)

typedef _Float16 h2 __attribute__((ext_vector_type(2)));
typedef _Float16 h8 __attribute__((ext_vector_type(8)));
typedef float    f4 __attribute__((ext_vector_type(4)));

#ifndef __has_builtin
#define __has_builtin(x) 0
#endif
#if __has_builtin(__builtin_amdgcn_fdot2)
__device__ __forceinline__ float fdot2_(h2 a, h2 b, float c) {
    return __builtin_amdgcn_fdot2(a, b, c, false);
}
#else
__device__ __forceinline__ float fdot2_(h2 a, h2 b, float c) {
    return c + (float)a.x * (float)b.x + (float)a.y * (float)b.y;
}
#endif

__device__ __forceinline__ h2 as_h2(unsigned int u) {
    union { unsigned int u; h2 h; } cv; cv.u = u; return cv.h;
}

__device__ __forceinline__ float sigmoid_fast(float x) {
    return __fdividef(1.f, 1.f + __expf(-x));
}
__device__ __forceinline__ float tanh_fast(float x) {
    return __fdividef(2.f, 1.f + __expf(-2.f * x)) - 1.f;
}

// ================= CSR build =================
__global__ __launch_bounds__(256) void hist_kernel(const int* __restrict__ dsts,
                                                   int* __restrict__ deg) {
    int i = blockIdx.x * 256 + threadIdx.x;
    if (i < NE) atomicAdd(&deg[dsts[i]], 1);
}

__global__ __launch_bounds__(512) void scan1_kernel(const int* __restrict__ deg,
                                                    int* __restrict__ loc,
                                                    int* __restrict__ bsum) {
    __shared__ int ws[8];
    const int b = blockIdx.x, t = threadIdx.x;
    const int idx = b * SCH + t;
    const int lane = t & 63, wv = t >> 6;
    int v = (t < SCH && idx < NN) ? deg[idx] : 0;
    int x = v;
    #pragma unroll
    for (int off = 1; off < 64; off <<= 1) {
        int y = __shfl_up(x, off);
        if (lane >= off) x += y;
    }
    if (lane == 63) ws[wv] = x;
    __syncthreads();
    if (t < 8) {
        int s = ws[t];
        #pragma unroll
        for (int off = 1; off < 8; off <<= 1) {
            int y = __shfl_up(s, off);
            if (t >= off) s += y;
        }
        ws[t] = s;
    }
    __syncthreads();
    const int base = wv ? ws[wv - 1] : 0;
    if (t < SCH && idx < NN) loc[idx] = base + x - v;
    if (t == 511) bsum[b] = ws[7];
}

__global__ void scan2_kernel(const int* __restrict__ bsum,
                             int* __restrict__ boff,
                             int* __restrict__ rowptr) {
    int tot = 0;
    for (int i = 0; i < SCB; ++i) { boff[i] = tot; tot += bsum[i]; }
    rowptr[NN] = tot;
}

__global__ __launch_bounds__(512) void scan3_kernel(const int* __restrict__ loc,
                                                    const int* __restrict__ boff,
                                                    int* __restrict__ rowptr,
                                                    int* __restrict__ head) {
    const int b = blockIdx.x, t = threadIdx.x;
    const int idx = b * SCH + t;
    if (t < SCH && idx < NN) {
        int r = loc[idx] + boff[b];
        rowptr[idx] = r;
        head[idx] = r;
    }
}

__global__ __launch_bounds__(256) void scatter_kernel(const int* __restrict__ srcs,
                                                      const int* __restrict__ dsts,
                                                      int* __restrict__ head,
                                                      int* __restrict__ seid,
                                                      int* __restrict__ ssrc,
                                                      int* __restrict__ sdst) {
    int e = blockIdx.x * 256 + threadIdx.x;
    if (e < NE) {
        int d = dsts[e];
        int pos = atomicAdd(&head[d], 1);
        seid[pos] = e;
        ssrc[pos] = srcs[e];
        sdst[pos] = d;
    }
}

// fp32 -> fp16 convert (linear), 4 elems/thread
__global__ __launch_bounds__(256) void cvt16_kernel(const float* __restrict__ in,
                                                    _Float16* __restrict__ o) {
    int i = blockIdx.x * 256 + threadIdx.x;
    float4 v = ((const float4*)in)[i];
    union { _Float16 h[4]; ushort4 u; } pk;
    pk.h[0] = (_Float16)v.x; pk.h[1] = (_Float16)v.y;
    pk.h[2] = (_Float16)v.z; pk.h[3] = (_Float16)v.w;
    ((ushort4*)o)[i] = pk.u;
}

// ========= fused edge pass: PERSISTENT, pipelined MFMA projection + segmented agg =========
// Tiles staged by GATHERING rows via seid (linear ea16 table — no permuted copy).
// Layer 0 warms the 102-MB ea16 in L3; layer 1's gathers mostly hit L3.
__global__ __launch_bounds__(256) void edge_mfma_kernel(
    const _Float16* __restrict__ h16,    // [NN][64] fp16 gather table
    const _Float16* __restrict__ ea16,   // [NE][64] fp16, ORIGINAL edge order
    const float*    __restrict__ W,      // [64][64] W[c][k]
    const float*    __restrict__ bias,   // [64]
    const int*      __restrict__ seid,   // original edge id per sorted pos
    const int*      __restrict__ ssrc,   // src per sorted pos
    const int*      __restrict__ sdst,   // dst per sorted pos
    float*          __restrict__ agg)    // [NN][64], pre-zeroed
{
    __shared__ _Float16 atile[64 * 64];  // 8 KB staged edge features (swizzled)
    __shared__ _Float16 etile[64 * 64];  // 8 KB projected e (swizzled)
    const int t    = threadIdx.x;
    const int lane = t & 63;
    const int w    = t >> 6;
    const int c15  = lane & 15;
    const int g    = lane >> 4;

    // B fragments (loaded ONCE per persistent block)
    h8 bfr[4][2];
    #pragma unroll
    for (int ct = 0; ct < 4; ++ct) {
        #pragma unroll
        for (int ks = 0; ks < 2; ++ks) {
            const float* wp = W + (size_t)(ct * 16 + c15) * 64 + ks * 32 + g * 8;
            float4 f0 = ((const float4*)wp)[0];
            float4 f1 = ((const float4*)wp)[1];
            h8 b;
            b[0] = (_Float16)f0.x; b[1] = (_Float16)f0.y;
            b[2] = (_Float16)f0.z; b[3] = (_Float16)f0.w;
            b[4] = (_Float16)f1.x; b[5] = (_Float16)f1.y;
            b[6] = (_Float16)f1.z; b[7] = (_Float16)f1.w;
            bfr[ct][ks] = b;
        }
    }
    float bi[4];
    #pragma unroll
    for (int ct = 0; ct < 4; ++ct) bi[ct] = bias[ct * 16 + c15];

    const int u0 = t, u1 = t + 256;                 // 16-B unit indices
    const int r0 = u0 >> 3, c0 = u0 & 7;            // tile row / 16-B col
    const int r1 = u1 >> 3, c1 = u1 & 7;
    const int off0 = c0 * 16, off1 = c1 * 16;
    uint4* const at0 = (uint4*)((char*)atile + r0 * 128 + (off0 ^ ((r0 & 7) << 4)));
    uint4* const at1 = (uint4*)((char*)atile + r1 * 128 + (off1 ^ ((r1 & 7) << 4)));

    int tile = blockIdx.x;
    {
        const int e0 = seid[tile * 64 + r0];
        const int e1 = seid[tile * 64 + r1];
        *at0 = *((const uint4*)(ea16 + (size_t)e0 * 64) + c0);
        *at1 = *((const uint4*)(ea16 + (size_t)e1 * 64) + c1);
    }
    __syncthreads();

    while (true) {
        const int next = tile + gridDim.x;

        // ---- MFMA projection from atile ----
        f4 acc[4];
        #pragma unroll
        for (int ct = 0; ct < 4; ++ct) { acc[ct][0]=0.f; acc[ct][1]=0.f; acc[ct][2]=0.f; acc[ct][3]=0.f; }
        const int arow = w * 16 + c15;
        #pragma unroll
        for (int ks = 0; ks < 2; ++ks) {
            h8 a = *(const h8*)((const char*)atile + arow * 128 +
                                ((ks * 64 + g * 16) ^ ((arow & 7) << 4)));
            #pragma unroll
            for (int ct = 0; ct < 4; ++ct)
                acc[ct] = __builtin_amdgcn_mfma_f32_16x16x32_f16(a, bfr[ct][ks], acc[ct], 0, 0, 0);
        }

        // ---- issue next tile's gather loads early (hide HBM/L3 latency) ----
        uint4 st0, st1;
        const bool more = (next < NTILES);
        if (more) {
            const int e0 = seid[next * 64 + r0];
            const int e1 = seid[next * 64 + r1];
            st0 = *((const uint4*)(ea16 + (size_t)e0 * 64) + c0);
            st1 = *((const uint4*)(ea16 + (size_t)e1 * 64) + c1);
        }

        // ---- write e (+bias) to wave-private etile ----
        #pragma unroll
        for (int ct = 0; ct < 4; ++ct) {
            #pragma unroll
            for (int r = 0; r < 4; ++r) {
                int slot = w * 16 + g * 4 + r;
                float v = acc[ct][r] + bi[ct];
                *(_Float16*)((char*)etile + slot * 128 +
                             (((ct * 16 + c15) * 2) ^ ((slot & 7) << 4))) = (_Float16)v;
            }
        }

        // ---- batch-prefetch metadata + h rows ----
        const int wbase = tile * 64 + w * 16;
        const int sdv = sdst[wbase + (lane & 15)];
        const int ssv = ssrc[wbase + (lane & 15)];
        float hv[16];
        #pragma unroll
        for (int i = 0; i < 16; ++i) {
            int sj = __shfl(ssv, i);
            hv[i] = (float)h16[(size_t)sj * HID + lane];
        }
        asm volatile("s_waitcnt lgkmcnt(0)" ::: "memory");

        // ---- segmented aggregation ----
        int prev = __shfl(sdv, 0);
        float accv = 0.f;
        #pragma unroll
        for (int i = 0; i < 16; ++i) {
            int d = __shfl(sdv, i);
            if (d != prev) {
                unsafeAtomicAdd(&agg[(size_t)prev * HID + lane], accv);
                accv = 0.f; prev = d;
            }
            const int slot = w * 16 + i;
            float ev = (float)*(const _Float16*)((const char*)etile + slot * 128 +
                                                 ((lane * 2) ^ ((slot & 7) << 4)));
            float m = ev + hv[i];
            accv += m > 0.f ? m : 0.f;
        }
        unsafeAtomicAdd(&agg[(size_t)prev * HID + lane], accv);

        if (!more) break;
        __syncthreads();
        *at0 = st0;
        *at1 = st1;
        tile = next;
        __syncthreads();
    }
}

// ---------------- node pass: fp16 LDS staging ----------------
__global__ __launch_bounds__(256) void node_kernel(
    const float* __restrict__ h_in,
    const float* __restrict__ agg,
    const float* __restrict__ W1, const float* __restrict__ b1,
    const float* __restrict__ W2, const float* __restrict__ b2,
    const float* __restrict__ epsp,
    const float* __restrict__ lnS, const float* __restrict__ lnB,
    float*       __restrict__ h_out,
    _Float16*    __restrict__ h16_out)   // may be null
{
    __shared__ _Float16 zbuf[4][64];
    __shared__ _Float16 tbuf[4][64];
    const int lane = threadIdx.x & 63;
    const int wid  = threadIdx.x >> 6;

    h2 w1h[32], w2h[32];
    {
        const float4* wf1 = (const float4*)(W1 + lane * 64);
        const float4* wf2 = (const float4*)(W2 + lane * 64);
        #pragma unroll
        for (int k4 = 0; k4 < 16; ++k4) {
            float4 a = wf1[k4], b = wf2[k4];
            h2 pa; pa.x = (_Float16)a.x; pa.y = (_Float16)a.y;
            h2 pb; pb.x = (_Float16)a.z; pb.y = (_Float16)a.w;
            w1h[2*k4] = pa; w1h[2*k4+1] = pb;
            h2 pc; pc.x = (_Float16)b.x; pc.y = (_Float16)b.y;
            h2 pd; pd.x = (_Float16)b.z; pd.y = (_Float16)b.w;
            w2h[2*k4] = pc; w2h[2*k4+1] = pd;
        }
    }
    const float b1c = b1[lane], b2c = b2[lane];
    const float sC = lnS[lane], bC = lnB[lane];
    const float epv = 1.f + epsp[0];

    const int gw = blockIdx.x * 4 + wid;
    const int nw = gridDim.x * 4;
    for (int n = gw; n < NN; n += nw) {
        float z = epv * h_in[(size_t)n*HID + lane] + agg[(size_t)n*HID + lane];
        zbuf[wid][lane] = (_Float16)z;
        asm volatile("s_waitcnt lgkmcnt(0)" ::: "memory");
        float acc = b1c;
        {
            const uint4* zf = (const uint4*)&zbuf[wid][0];
            #pragma unroll
            for (int k = 0; k < 8; ++k) {
                uint4 u = zf[k];
                acc = fdot2_(as_h2(u.x), w1h[4*k+0], acc);
                acc = fdot2_(as_h2(u.y), w1h[4*k+1], acc);
                acc = fdot2_(as_h2(u.z), w1h[4*k+2], acc);
                acc = fdot2_(as_h2(u.w), w1h[4*k+3], acc);
            }
        }
        acc = acc > 0.f ? acc : 0.f;
        tbuf[wid][lane] = (_Float16)acc;
        asm volatile("s_waitcnt lgkmcnt(0)" ::: "memory");
        float acc2 = b2c;
        {
            const uint4* tf = (const uint4*)&tbuf[wid][0];
            #pragma unroll
            for (int k = 0; k < 8; ++k) {
                uint4 u = tf[k];
                acc2 = fdot2_(as_h2(u.x), w2h[4*k+0], acc2);
                acc2 = fdot2_(as_h2(u.y), w2h[4*k+1], acc2);
                acc2 = fdot2_(as_h2(u.z), w2h[4*k+2], acc2);
                acc2 = fdot2_(as_h2(u.w), w2h[4*k+3], acc2);
            }
        }
        float s1 = acc2, s2 = acc2 * acc2;
        #pragma unroll
        for (int off = 32; off >= 1; off >>= 1) {
            s1 += __shfl_xor(s1, off);
            s2 += __shfl_xor(s2, off);
        }
        float mu  = s1 * (1.f/64.f);
        float var = s2 * (1.f/64.f) - mu * mu;
        float r   = rsqrtf(var + 1e-5f);
        float o   = (acc2 - mu) * r * sC + bC;
        float ov  = o > 0.f ? o : 0.f;
        h_out[(size_t)n*HID + lane] = ov;
        if (h16_out) h16_out[(size_t)n*HID + lane] = (_Float16)ov;
    }
}

// ---------------- prep: W2T transpose + selp = b_ih + sel @ W_ih[:, :64]^T ----------------
// stored PERMUTED to lstm thread order: gate g -> pos = (j<<2)|((gt&1)<<1)|(gt>>1)
__global__ __launch_bounds__(512) void prep_kernel(
    const float* __restrict__ Wih,   // [512][96]
    const float* __restrict__ bih,   // [512]
    const float* __restrict__ h2v,   // [NN][64]
    const int*   __restrict__ nidx,  // [64]
    float*       __restrict__ W2T,   // [32][512] permuted cols
    float*       __restrict__ selp)  // [64][512] permuted cols
{
    const int g  = threadIdx.x;                       // gate index 0..511
    const int j_ = g & 127, gt_ = g >> 7;
    const int pos = (j_ << 2) | ((gt_ & 1) << 1) | (gt_ >> 1);
    if (blockIdx.x == BB) {
        #pragma unroll
        for (int k = 0; k < 32; ++k)
            W2T[k * G4 + pos] = Wih[g * 96 + 64 + k];
    } else {
        const int b = blockIdx.x;
        __shared__ float hrow[64];
        if (g < 64) hrow[g] = h2v[(size_t)nidx[b] * HID + g];
        __syncthreads();
        float acc = bih[g];
        #pragma unroll
        for (int k = 0; k < 64; ++k)
            acc = fmaf(hrow[k], Wih[g * 96 + k], acc);
        selp[b * G4 + pos] = acc;
    }
}

// ---------------- xp[t][b][pos] = selp[b][pos] + x_seq[b][t] @ W2T[:,pos] ----------------
__global__ __launch_bounds__(512) void xp_kernel(
    const float* __restrict__ xseq,  // [B][T][32]
    const float* __restrict__ selp,  // [B][512] permuted
    const float* __restrict__ W2T,   // [32][512] permuted
    float*       __restrict__ xp)    // [T][B][512] permuted
{
    const int g   = threadIdx.x;
    const int row = blockIdx.x;      // row = t*64 + b
    const int t   = row >> 6;
    const int b   = row & 63;
    __shared__ float xs[32];
    if (g < 32) xs[g] = xseq[((size_t)b * TT + t) * 32 + g];
    __syncthreads();
    float acc = selp[b * G4 + g];
    #pragma unroll
    for (int k = 0; k < 32; ++k)
        acc = fmaf(xs[k], W2T[k * G4 + g], acc);
    xp[(size_t)row * G4 + g] = acc;
}

// ---------------- LSTM recurrence + final LN + fc ----------------
// 64 blocks x 256 threads (4 waves). Thread t = (p = t&1, j = t>>1) owns gates
// (p, p+2) of unit j. HALF-H SPLIT: each thread reads only h-half p (8 x
// ds_read_b128) and computes partials over that half for its own 2 gates AND
// its lane^1 partner's 2 gates; full dots recovered with two shfl_xor adds.
__global__ __launch_bounds__(256) void lstm_kernel(
    const float* __restrict__ xp,    // [T][B][512] thread-order
    const float* __restrict__ Whh,   // [512][128]
    const float* __restrict__ bhh,   // [512]
    const float* __restrict__ lnS, const float* __restrict__ lnB,  // [128]
    const float* __restrict__ fcW,   // [1][128]
    const float* __restrict__ fcb,   // [1]
    float*       __restrict__ out)   // [64]
{
    const int t  = threadIdx.x;      // 0..255
    const int b  = blockIdx.x;
    const int p  = t & 1;
    const int j  = t >> 1;           // hidden unit 0..127
    const int g0 = p * LH + j;            // own: type p   (i or f)
    const int g1 = (p + 2) * LH + j;      // own: type p+2 (g or o)
    const int q0 = (p ^ 1) * LH + j;      // partner's type
    const int q1 = ((p ^ 1) + 2) * LH + j;
    const int co = p * 64;                // this thread's h-half column offset

    // 4 half-rows of Whh (64 halfs each) -> 128 VGPRs total
    h2 wA[32], wB[32], wC[32], wD[32];
    {
        const float4* f0 = (const float4*)(Whh + (size_t)g0 * LH + co);
        const float4* f1 = (const float4*)(Whh + (size_t)g1 * LH + co);
        const float4* f2 = (const float4*)(Whh + (size_t)q0 * LH + co);
        const float4* f3 = (const float4*)(Whh + (size_t)q1 * LH + co);
        #pragma unroll
        for (int k4 = 0; k4 < 16; ++k4) {
            float4 v;
            v = f0[k4];
            { h2 a; a.x=(_Float16)v.x; a.y=(_Float16)v.y; wA[2*k4]=a;
              h2 c2; c2.x=(_Float16)v.z; c2.y=(_Float16)v.w; wA[2*k4+1]=c2; }
            v = f1[k4];
            { h2 a; a.x=(_Float16)v.x; a.y=(_Float16)v.y; wB[2*k4]=a;
              h2 c2; c2.x=(_Float16)v.z; c2.y=(_Float16)v.w; wB[2*k4+1]=c2; }
            v = f2[k4];
            { h2 a; a.x=(_Float16)v.x; a.y=(_Float16)v.y; wC[2*k4]=a;
              h2 c2; c2.x=(_Float16)v.z; c2.y=(_Float16)v.w; wC[2*k4+1]=c2; }
            v = f3[k4];
            { h2 a; a.x=(_Float16)v.x; a.y=(_Float16)v.y; wD[2*k4]=a;
              h2 c2; c2.x=(_Float16)v.z; c2.y=(_Float16)v.w; wD[2*k4+1]=c2; }
        }
    }
    const float bg0 = bhh[g0];
    const float bg1 = bhh[g1];
    const float s1_ = (p == 0) ? 2.f : 1.f;
    const float a1_ = (p == 0) ? 2.f : 1.f;
    const float d1_ = (p == 0) ? -1.f : 0.f;

    __shared__ _Float16 hb[2][LH];        // fp16 h, double buffered
    __shared__ float h_final[LH];
    if (t < 64) ((unsigned int*)&hb[0][0])[t] = 0u;
    float c = 0.f;
    float h_last = 0.f;
    __syncthreads();

    float2 xv = ((const float2*)(xp + (size_t)b * G4))[t];   // t=0 slice

    auto step = [&](const _Float16* hbR, _Float16* hbW, int ts) {
        const int tn = (ts + 1 < TT) ? ts + 1 : ts;
        const float2 xn = ((const float2*)(xp + ((size_t)tn * BB + b) * G4))[t];

        // read only this thread's h-half: 8 x ds_read_b128
        const uint4* hb4 = (const uint4*)(hbR + co);
        float sA0 = 0.f, sA1 = 0.f;
        float sB0 = 0.f, sB1 = 0.f;
        float sC0 = 0.f, sC1 = 0.f;
        float sD0 = 0.f, sD1 = 0.f;
        #pragma unroll
        for (int k = 0; k < 8; ++k) {
            uint4 u = hb4[k];
            h2 p0 = as_h2(u.x), p1 = as_h2(u.y), p2 = as_h2(u.z), p3 = as_h2(u.w);
            sA0 = fdot2_(p0, wA[4*k+0], sA0);
            sA1 = fdot2_(p1, wA[4*k+1], sA1);
            sA0 = fdot2_(p2, wA[4*k+2], sA0);
            sA1 = fdot2_(p3, wA[4*k+3], sA1);
            sB0 = fdot2_(p0, wB[4*k+0], sB0);
            sB1 = fdot2_(p1, wB[4*k+1], sB1);
            sB0 = fdot2_(p2, wB[4*k+2], sB0);
            sB1 = fdot2_(p3, wB[4*k+3], sB1);
            sC0 = fdot2_(p0, wC[4*k+0], sC0);
            sC1 = fdot2_(p1, wC[4*k+1], sC1);
            sC0 = fdot2_(p2, wC[4*k+2], sC0);
            sC1 = fdot2_(p3, wC[4*k+3], sC1);
            sD0 = fdot2_(p0, wD[4*k+0], sD0);
            sD1 = fdot2_(p1, wD[4*k+1], sD1);
            sD0 = fdot2_(p2, wD[4*k+2], sD0);
            sD1 = fdot2_(p3, wD[4*k+3], sD1);
        }
        const float sOwn0 = sA0 + sA1;
        const float sOwn1 = sB0 + sB1;
        const float sPar0 = sC0 + sC1;
        const float sPar1 = sD0 + sD1;
        const float gfull0 = sOwn0 + __shfl_xor(sPar0, 1) + bg0 + xv.x;
        const float gfull1 = sOwn1 + __shfl_xor(sPar1, 1) + bg1 + xv.y;

        float act0 = sigmoid_fast(gfull0);                                        // i or f
        float act1 = fmaf(a1_, __fdividef(1.f, 1.f + __expf(-s1_ * gfull1)), d1_); // g or o

        float o0 = __shfl_xor(act0, 1);
        float o1 = __shfl_xor(act1, 1);
        float iv = p ? o0 : act0;
        float fv = p ? act0 : o0;
        float gv = p ? o1 : act1;
        float ov = p ? act1 : o1;

        c = fmaf(fv, c, iv * gv);
        h_last = ov * tanh_fast(c);

        if (p == 0) hbW[j] = (_Float16)h_last;    // ds_write_b16, even lanes
        __syncthreads();

        xv = xn;
    };

    for (int ts = 0; ts < TT; ts += 2) {
        step(&hb[0][0], &hb[1][0], ts);
        step(&hb[1][0], &hb[0][0], ts + 1);
    }

    if (p == 0) h_final[j] = h_last;
    __syncthreads();
    if (t < 64) {
        float h0 = h_final[t], h1 = h_final[t + 64];
        float s1 = h0 + h1, s2 = h0*h0 + h1*h1;
        #pragma unroll
        for (int off = 32; off >= 1; off >>= 1) {
            s1 += __shfl_xor(s1, off);
            s2 += __shfl_xor(s2, off);
        }
        float mu  = s1 * (1.f/128.f);
        float var = s2 * (1.f/128.f) - mu * mu;
        float rr  = rsqrtf(var + 1e-5f);
        float pv = ((h0 - mu)*rr*lnS[t]      + lnB[t])      * fcW[t]
                 + ((h1 - mu)*rr*lnS[t + 64] + lnB[t + 64]) * fcW[t + 64];
        #pragma unroll
        for (int off = 32; off >= 1; off >>= 1) pv += __shfl_xor(pv, off);
        if (t == 0) out[b] = pv + fcb[0];
    }
}

extern "C" void kernel_launch(void* const* d_in, const int* in_sizes, int n_in,
                              void* d_out, int out_size, void* d_ws, size_t ws_size,
                              hipStream_t stream) {
    const float* x     = (const float*)d_in[0];
    const float* ea    = (const float*)d_in[1];
    const float* xseq  = (const float*)d_in[2];
    const float* linW  = (const float*)d_in[3];
    const float* linB  = (const float*)d_in[4];
    const float* mW1   = (const float*)d_in[5];
    const float* mb1   = (const float*)d_in[6];
    const float* mW2   = (const float*)d_in[7];
    const float* mb2   = (const float*)d_in[8];
    const float* eps   = (const float*)d_in[9];
    const float* lnS   = (const float*)d_in[10];
    const float* lnB   = (const float*)d_in[11];
    const float* Wih   = (const float*)d_in[12];
    const float* Whh   = (const float*)d_in[13];
    const float* bih   = (const float*)d_in[14];
    const float* bhh   = (const float*)d_in[15];
    const float* llnS  = (const float*)d_in[16];
    const float* llnB  = (const float*)d_in[17];
    const float* fcW   = (const float*)d_in[18];
    const float* fcb   = (const float*)d_in[19];
    const int*   eidx  = (const int*)d_in[20];
    const int*   nidx  = (const int*)d_in[21];
    float* out = (float*)d_out;

    const int* srcs = eidx;
    const int* dsts = eidx + NE;

    // workspace layout
    float* ws   = (float*)d_ws;
    float* agg  = ws;                              // NN*64
    float* h1   = agg  + (size_t)NN * HID;
    float* h2m  = h1   + (size_t)NN * HID;
    float* selp = h2m  + (size_t)NN * HID;         // BB*G4
    float* W2T  = selp + (size_t)BB * G4;          // 32*G4
    float* xp   = W2T  + (size_t)32 * G4;          // TT*BB*G4
    int*   deg    = (int*)(xp + (size_t)TT * BB * G4);  // NN
    int*   rowptr = deg + NN;                      // NN+1
    int*   head   = rowptr + NN + 2;               // NN
    int*   loc    = head + NN;                     // NN
    int*   bsum   = loc + NN;                      // SCB
    int*   boff   = bsum + SCB + 3;                // SCB
    int*   seid   = boff + SCB + 3;                // NE (sorted pos -> edge id)
    int*   ssrc   = seid + NE;                     // NE
    int*   sdst   = ssrc + NE;                     // NE
    uintptr_t ep = (uintptr_t)(sdst + NE);
    ep = (ep + 15) & ~(uintptr_t)15;
    _Float16* ea16  = (_Float16*)ep;               // NE*64 halfs = 102.4 MB (linear)
    _Float16* x16   = ea16 + (size_t)NE * HID;     // NN*64 halfs
    _Float16* h1_16 = x16 + (size_t)NN * HID;      // NN*64 halfs

    const size_t aggBytes = (size_t)NN * HID * sizeof(float);

    // ---- CSR build + linear fp16 tables (shared by both layers) ----
    hipMemsetAsync(deg, 0, (size_t)NN * sizeof(int), stream);
    hist_kernel<<<(NE + 255) / 256, 256, 0, stream>>>(dsts, deg);
    scan1_kernel<<<SCB, 512, 0, stream>>>(deg, loc, bsum);
    scan2_kernel<<<1, 1, 0, stream>>>(bsum, boff, rowptr);
    scan3_kernel<<<SCB, 512, 0, stream>>>(loc, boff, rowptr, head);
    scatter_kernel<<<(NE + 255) / 256, 256, 0, stream>>>(srcs, dsts, head, seid, ssrc, sdst);
    cvt16_kernel<<<NE * HID / 4 / 256, 256, 0, stream>>>(ea, ea16);
    cvt16_kernel<<<NN * HID / 4 / 256, 256, 0, stream>>>(x, x16);

    // ---- layer 0 ----
    hipMemsetAsync(agg, 0, aggBytes, stream);
    edge_mfma_kernel<<<2048, 256, 0, stream>>>(x16, ea16, linW, linB, seid, ssrc, sdst, agg);
    node_kernel<<<512, 256, 0, stream>>>(x, agg, mW1, mb1, mW2, mb2, eps, lnS, lnB, h1, h1_16);
    // ---- layer 1 ----
    hipMemsetAsync(agg, 0, aggBytes, stream);
    edge_mfma_kernel<<<2048, 256, 0, stream>>>(h1_16, ea16, linW + 64*64, linB + 64, seid, ssrc, sdst, agg);
    node_kernel<<<512, 256, 0, stream>>>(h1, agg, mW1 + 64*64, mb1 + 64, mW2 + 64*64, mb2 + 64,
                                         eps + 1, lnS + 64, lnB + 64, h2m, (_Float16*)nullptr);
    // ---- LSTM input projection (permuted to lstm thread order) ----
    prep_kernel<<<BB + 1, 512, 0, stream>>>(Wih, bih, h2m, nidx, W2T, selp);
    xp_kernel<<<TT * BB, 512, 0, stream>>>(xseq, selp, W2T, xp);
    // ---- LSTM recurrence + head (256 threads, half-h split) ----
    lstm_kernel<<<BB, 256, 0, stream>>>(xp, Whh, bhh, llnS, llnB, fcW, fcb, out);
}

// Round 17
// 542.322 us; speedup vs baseline: 1.0586x; 1.0586x over previous
//
#include <hip/hip_runtime.h>
#include <cmath>

static constexpr int NN  = 50000;   // nodes
static constexpr int NE  = 800000;  // edges
static constexpr int HID = 64;
static constexpr int BB  = 64;      // batch
static constexpr int TT  = 200;     // seq len
static constexpr int LH  = 128;     // lstm hidden
static constexpr int G4  = 512;     // 4*LH
static constexpr int NTILES = NE / 64;   // 12500

static constexpr int SCB = 125;     // scan blocks
static constexpr int SCH = 400;     // elems per scan block (125*400 = 50000)

static constexpr int HBLK = (NE + 255) / 256;        // 3125 hist blocks
static constexpr int XBLK = NN * HID / 4 / 256;      // 3125 cvt-x blocks
static constexpr int PBLK = NE / 16;                 // 50000 permute blocks
static constexpr int ZBLK = NN * HID / 4 / 256;      // 3125 agg-zero blocks

typedef _Float16 h2 __attribute__((ext_vector_type(2)));
typedef _Float16 h8 __attribute__((ext_vector_type(8)));
typedef float    f4 __attribute__((ext_vector_type(4)));

#ifndef __has_builtin
#define __has_builtin(x) 0
#endif
#if __has_builtin(__builtin_amdgcn_fdot2)
__device__ __forceinline__ float fdot2_(h2 a, h2 b, float c) {
    return __builtin_amdgcn_fdot2(a, b, c, false);
}
#else
__device__ __forceinline__ float fdot2_(h2 a, h2 b, float c) {
    return c + (float)a.x * (float)b.x + (float)a.y * (float)b.y;
}
#endif

__device__ __forceinline__ h2 as_h2(unsigned int u) {
    union { unsigned int u; h2 h; } cv; cv.u = u; return cv.h;
}

__device__ __forceinline__ float sigmoid_fast(float x) {
    return __fdividef(1.f, 1.f + __expf(-x));
}
__device__ __forceinline__ float tanh_fast(float x) {
    return __fdividef(2.f, 1.f + __expf(-2.f * x)) - 1.f;
}

// ================= CSR build =================
// fused: hist (blocks < HBLK) + x fp32->fp16 convert (blocks >= HBLK)
__global__ __launch_bounds__(256) void hist_cvtx_kernel(const int* __restrict__ dsts,
                                                        int* __restrict__ deg,
                                                        const float* __restrict__ x,
                                                        _Float16* __restrict__ x16) {
    if (blockIdx.x < HBLK) {
        int i = blockIdx.x * 256 + threadIdx.x;
        if (i < NE) atomicAdd(&deg[dsts[i]], 1);
    } else {
        int i = (blockIdx.x - HBLK) * 256 + threadIdx.x;
        float4 v = ((const float4*)x)[i];
        union { _Float16 h[4]; ushort4 u; } pk;
        pk.h[0] = (_Float16)v.x; pk.h[1] = (_Float16)v.y;
        pk.h[2] = (_Float16)v.z; pk.h[3] = (_Float16)v.w;
        ((ushort4*)x16)[i] = pk.u;
    }
}

__global__ __launch_bounds__(512) void scan1_kernel(const int* __restrict__ deg,
                                                    int* __restrict__ loc,
                                                    int* __restrict__ bsum) {
    __shared__ int ws[8];
    const int b = blockIdx.x, t = threadIdx.x;
    const int idx = b * SCH + t;
    const int lane = t & 63, wv = t >> 6;
    int v = (t < SCH && idx < NN) ? deg[idx] : 0;
    int x = v;
    #pragma unroll
    for (int off = 1; off < 64; off <<= 1) {
        int y = __shfl_up(x, off);
        if (lane >= off) x += y;
    }
    if (lane == 63) ws[wv] = x;
    __syncthreads();
    if (t < 8) {
        int s = ws[t];
        #pragma unroll
        for (int off = 1; off < 8; off <<= 1) {
            int y = __shfl_up(s, off);
            if (t >= off) s += y;
        }
        ws[t] = s;
    }
    __syncthreads();
    const int base = wv ? ws[wv - 1] : 0;
    if (t < SCH && idx < NN) loc[idx] = base + x - v;
    if (t == 511) bsum[b] = ws[7];
}

__global__ void scan2_kernel(const int* __restrict__ bsum,
                             int* __restrict__ boff,
                             int* __restrict__ rowptr) {
    int tot = 0;
    for (int i = 0; i < SCB; ++i) { boff[i] = tot; tot += bsum[i]; }
    rowptr[NN] = tot;
}

__global__ __launch_bounds__(512) void scan3_kernel(const int* __restrict__ loc,
                                                    const int* __restrict__ boff,
                                                    int* __restrict__ rowptr,
                                                    int* __restrict__ head) {
    const int b = blockIdx.x, t = threadIdx.x;
    const int idx = b * SCH + t;
    if (t < SCH && idx < NN) {
        int r = loc[idx] + boff[b];
        rowptr[idx] = r;
        head[idx] = r;
    }
}

__global__ __launch_bounds__(256) void scatter_kernel(const int* __restrict__ srcs,
                                                      const int* __restrict__ dsts,
                                                      int* __restrict__ head,
                                                      int* __restrict__ perm,
                                                      int* __restrict__ ssrc,
                                                      int* __restrict__ sdst) {
    int e = blockIdx.x * 256 + threadIdx.x;
    if (e < NE) {
        int d = dsts[e];
        int pos = atomicAdd(&head[d], 1);
        perm[e] = pos;
        ssrc[pos] = srcs[e];
        sdst[pos] = d;
    }
}

// permute edge_attr into dst-sorted order, fp32 -> fp16 (scatter mode, one-time)
// fused: blocks >= PBLK zero the agg buffer for layer 0.
__global__ __launch_bounds__(256) void permute_zero_kernel(const float* __restrict__ ea,
                                                           const int* __restrict__ perm,
                                                           ushort4* __restrict__ easort,
                                                           float* __restrict__ agg) {
    if (blockIdx.x < PBLK) {
        const int lane = threadIdx.x & 63, wid = threadIdx.x >> 6;
        const int slot = lane >> 4, hw = lane & 15;
        const int e = (blockIdx.x * 4 + wid) * 4 + slot;
        if (e < NE) {
            const int p = perm[e];
            float4 v = ((const float4*)ea)[(size_t)e * 16 + hw];
            union { _Float16 h[4]; ushort4 u; } pk;
            pk.h[0] = (_Float16)v.x; pk.h[1] = (_Float16)v.y;
            pk.h[2] = (_Float16)v.z; pk.h[3] = (_Float16)v.w;
            easort[(size_t)p * 16 + hw] = pk.u;
        }
    } else {
        int i = (blockIdx.x - PBLK) * 256 + threadIdx.x;
        ((float4*)agg)[i] = make_float4(0.f, 0.f, 0.f, 0.f);
    }
}

// ========= fused edge pass: PERSISTENT, pipelined MFMA projection + segmented agg =========
__global__ __launch_bounds__(256) void edge_mfma_kernel(
    const _Float16* __restrict__ h16,    // [NN][64] fp16 gather table
    const _Float16* __restrict__ easort, // [NE][64] fp16, dst-sorted
    const float*    __restrict__ W,      // [64][64] W[c][k]
    const float*    __restrict__ bias,   // [64]
    const int*      __restrict__ ssrc,   // src per sorted pos
    const int*      __restrict__ sdst,   // dst per sorted pos
    float*          __restrict__ agg)    // [NN][64], pre-zeroed
{
    __shared__ _Float16 atile[64 * 64];  // 8 KB staged edge features (swizzled)
    __shared__ _Float16 etile[64 * 64];  // 8 KB projected e (swizzled)
    const int t    = threadIdx.x;
    const int lane = t & 63;
    const int w    = t >> 6;
    const int c15  = lane & 15;
    const int g    = lane >> 4;

    // B fragments (loaded ONCE per persistent block)
    h8 bfr[4][2];
    #pragma unroll
    for (int ct = 0; ct < 4; ++ct) {
        #pragma unroll
        for (int ks = 0; ks < 2; ++ks) {
            const float* wp = W + (size_t)(ct * 16 + c15) * 64 + ks * 32 + g * 8;
            float4 f0 = ((const float4*)wp)[0];
            float4 f1 = ((const float4*)wp)[1];
            h8 b;
            b[0] = (_Float16)f0.x; b[1] = (_Float16)f0.y;
            b[2] = (_Float16)f0.z; b[3] = (_Float16)f0.w;
            b[4] = (_Float16)f1.x; b[5] = (_Float16)f1.y;
            b[6] = (_Float16)f1.z; b[7] = (_Float16)f1.w;
            bfr[ct][ks] = b;
        }
    }
    float bi[4];
    #pragma unroll
    for (int ct = 0; ct < 4; ++ct) bi[ct] = bias[ct * 16 + c15];

    const int u0 = t, u1 = t + 256;                 // 16-B unit indices
    const int row0 = u0 >> 3, off0 = (u0 & 7) * 16;
    const int row1 = u1 >> 3, off1 = (u1 & 7) * 16;
    uint4* const at0 = (uint4*)((char*)atile + row0 * 128 + (off0 ^ ((row0 & 7) << 4)));
    uint4* const at1 = (uint4*)((char*)atile + row1 * 128 + (off1 ^ ((row1 & 7) << 4)));

    int tile = blockIdx.x;
    {
        const uint4* src = (const uint4*)(easort + (size_t)tile * 64 * 64);
        *at0 = src[u0];
        *at1 = src[u1];
    }
    __syncthreads();

    while (true) {
        const int next = tile + gridDim.x;

        // ---- MFMA projection from atile ----
        f4 acc[4];
        #pragma unroll
        for (int ct = 0; ct < 4; ++ct) { acc[ct][0]=0.f; acc[ct][1]=0.f; acc[ct][2]=0.f; acc[ct][3]=0.f; }
        const int arow = w * 16 + c15;
        #pragma unroll
        for (int ks = 0; ks < 2; ++ks) {
            h8 a = *(const h8*)((const char*)atile + arow * 128 +
                                ((ks * 64 + g * 16) ^ ((arow & 7) << 4)));
            #pragma unroll
            for (int ct = 0; ct < 4; ++ct)
                acc[ct] = __builtin_amdgcn_mfma_f32_16x16x32_f16(a, bfr[ct][ks], acc[ct], 0, 0, 0);
        }

        // ---- issue next tile's staging loads early ----
        uint4 st0, st1;
        const bool more = (next < NTILES);
        if (more) {
            const uint4* src = (const uint4*)(easort + (size_t)next * 64 * 64);
            st0 = src[u0];
            st1 = src[u1];
        }

        // ---- write e (+bias) to wave-private etile ----
        #pragma unroll
        for (int ct = 0; ct < 4; ++ct) {
            #pragma unroll
            for (int r = 0; r < 4; ++r) {
                int slot = w * 16 + g * 4 + r;
                float v = acc[ct][r] + bi[ct];
                *(_Float16*)((char*)etile + slot * 128 +
                             (((ct * 16 + c15) * 2) ^ ((slot & 7) << 4))) = (_Float16)v;
            }
        }

        // ---- batch-prefetch metadata + h rows ----
        const int wbase = tile * 64 + w * 16;
        const int sdv = sdst[wbase + (lane & 15)];
        const int ssv = ssrc[wbase + (lane & 15)];
        float hv[16];
        #pragma unroll
        for (int i = 0; i < 16; ++i) {
            int sj = __shfl(ssv, i);
            hv[i] = (float)h16[(size_t)sj * HID + lane];
        }
        asm volatile("s_waitcnt lgkmcnt(0)" ::: "memory");

        // ---- segmented aggregation ----
        int prev = __shfl(sdv, 0);
        float accv = 0.f;
        #pragma unroll
        for (int i = 0; i < 16; ++i) {
            int d = __shfl(sdv, i);
            if (d != prev) {
                unsafeAtomicAdd(&agg[(size_t)prev * HID + lane], accv);
                accv = 0.f; prev = d;
            }
            const int slot = w * 16 + i;
            float ev = (float)*(const _Float16*)((const char*)etile + slot * 128 +
                                                 ((lane * 2) ^ ((slot & 7) << 4)));
            float m = ev + hv[i];
            accv += m > 0.f ? m : 0.f;
        }
        unsafeAtomicAdd(&agg[(size_t)prev * HID + lane], accv);

        if (!more) break;
        __syncthreads();
        *at0 = st0;
        *at1 = st1;
        tile = next;
        __syncthreads();
    }
}

// ---------------- node pass: fp16 LDS staging ----------------
__global__ __launch_bounds__(256) void node_kernel(
    const float* __restrict__ h_in,
    const float* __restrict__ agg,
    const float* __restrict__ W1, const float* __restrict__ b1,
    const float* __restrict__ W2, const float* __restrict__ b2,
    const float* __restrict__ epsp,
    const float* __restrict__ lnS, const float* __restrict__ lnB,
    float*       __restrict__ h_out,
    _Float16*    __restrict__ h16_out)   // may be null
{
    __shared__ _Float16 zbuf[4][64];
    __shared__ _Float16 tbuf[4][64];
    const int lane = threadIdx.x & 63;
    const int wid  = threadIdx.x >> 6;

    h2 w1h[32], w2h[32];
    {
        const float4* wf1 = (const float4*)(W1 + lane * 64);
        const float4* wf2 = (const float4*)(W2 + lane * 64);
        #pragma unroll
        for (int k4 = 0; k4 < 16; ++k4) {
            float4 a = wf1[k4], b = wf2[k4];
            h2 pa; pa.x = (_Float16)a.x; pa.y = (_Float16)a.y;
            h2 pb; pb.x = (_Float16)a.z; pb.y = (_Float16)a.w;
            w1h[2*k4] = pa; w1h[2*k4+1] = pb;
            h2 pc; pc.x = (_Float16)b.x; pc.y = (_Float16)b.y;
            h2 pd; pd.x = (_Float16)b.z; pd.y = (_Float16)b.w;
            w2h[2*k4] = pc; w2h[2*k4+1] = pd;
        }
    }
    const float b1c = b1[lane], b2c = b2[lane];
    const float sC = lnS[lane], bC = lnB[lane];
    const float epv = 1.f + epsp[0];

    const int gw = blockIdx.x * 4 + wid;
    const int nw = gridDim.x * 4;
    for (int n = gw; n < NN; n += nw) {
        float z = epv * h_in[(size_t)n*HID + lane] + agg[(size_t)n*HID + lane];
        zbuf[wid][lane] = (_Float16)z;
        asm volatile("s_waitcnt lgkmcnt(0)" ::: "memory");
        float acc = b1c;
        {
            const uint4* zf = (const uint4*)&zbuf[wid][0];
            #pragma unroll
            for (int k = 0; k < 8; ++k) {
                uint4 u = zf[k];
                acc = fdot2_(as_h2(u.x), w1h[4*k+0], acc);
                acc = fdot2_(as_h2(u.y), w1h[4*k+1], acc);
                acc = fdot2_(as_h2(u.z), w1h[4*k+2], acc);
                acc = fdot2_(as_h2(u.w), w1h[4*k+3], acc);
            }
        }
        acc = acc > 0.f ? acc : 0.f;
        tbuf[wid][lane] = (_Float16)acc;
        asm volatile("s_waitcnt lgkmcnt(0)" ::: "memory");
        float acc2 = b2c;
        {
            const uint4* tf = (const uint4*)&tbuf[wid][0];
            #pragma unroll
            for (int k = 0; k < 8; ++k) {
                uint4 u = tf[k];
                acc2 = fdot2_(as_h2(u.x), w2h[4*k+0], acc2);
                acc2 = fdot2_(as_h2(u.y), w2h[4*k+1], acc2);
                acc2 = fdot2_(as_h2(u.z), w2h[4*k+2], acc2);
                acc2 = fdot2_(as_h2(u.w), w2h[4*k+3], acc2);
            }
        }
        float s1 = acc2, s2 = acc2 * acc2;
        #pragma unroll
        for (int off = 32; off >= 1; off >>= 1) {
            s1 += __shfl_xor(s1, off);
            s2 += __shfl_xor(s2, off);
        }
        float mu  = s1 * (1.f/64.f);
        float var = s2 * (1.f/64.f) - mu * mu;
        float r   = rsqrtf(var + 1e-5f);
        float o   = (acc2 - mu) * r * sC + bC;
        float ov  = o > 0.f ? o : 0.f;
        h_out[(size_t)n*HID + lane] = ov;
        if (h16_out) h16_out[(size_t)n*HID + lane] = (_Float16)ov;
    }
}

// ---------------- prep: W2T transpose + selp = b_ih + sel @ W_ih[:, :64]^T ----------------
// stored PERMUTED to lstm thread order: gate g -> pos = (j<<2)|((gt&1)<<1)|(gt>>1)
__global__ __launch_bounds__(512) void prep_kernel(
    const float* __restrict__ Wih,   // [512][96]
    const float* __restrict__ bih,   // [512]
    const float* __restrict__ h2v,   // [NN][64]
    const int*   __restrict__ nidx,  // [64]
    float*       __restrict__ W2T,   // [32][512] permuted cols
    float*       __restrict__ selp)  // [64][512] permuted cols
{
    const int g  = threadIdx.x;                       // gate index 0..511
    const int j_ = g & 127, gt_ = g >> 7;
    const int pos = (j_ << 2) | ((gt_ & 1) << 1) | (gt_ >> 1);
    if (blockIdx.x == BB) {
        #pragma unroll
        for (int k = 0; k < 32; ++k)
            W2T[k * G4 + pos] = Wih[g * 96 + 64 + k];
    } else {
        const int b = blockIdx.x;
        __shared__ float hrow[64];
        if (g < 64) hrow[g] = h2v[(size_t)nidx[b] * HID + g];
        __syncthreads();
        float acc = bih[g];
        #pragma unroll
        for (int k = 0; k < 64; ++k)
            acc = fmaf(hrow[k], Wih[g * 96 + k], acc);
        selp[b * G4 + pos] = acc;
    }
}

// ---------------- xp (fp16) [t][b][pos] = selp[b][pos] + x_seq[b][t] @ W2T[:,pos] ----------------
__global__ __launch_bounds__(512) void xp_kernel(
    const float* __restrict__ xseq,  // [B][T][32]
    const float* __restrict__ selp,  // [B][512] permuted
    const float* __restrict__ W2T,   // [32][512] permuted
    _Float16*    __restrict__ xp)    // [T][B][512] permuted, fp16
{
    const int g   = threadIdx.x;
    const int row = blockIdx.x;      // row = t*64 + b
    const int t   = row >> 6;
    const int b   = row & 63;
    __shared__ float xs[32];
    if (g < 32) xs[g] = xseq[((size_t)b * TT + t) * 32 + g];
    __syncthreads();
    float acc = selp[b * G4 + g];
    #pragma unroll
    for (int k = 0; k < 32; ++k)
        acc = fmaf(xs[k], W2T[k * G4 + g], acc);
    xp[(size_t)row * G4 + g] = (_Float16)acc;
}

// ---------------- LSTM recurrence + final LN + fc ----------------
// 64 blocks x 256 threads (4 waves). Thread t = (p = t&1, j = t>>1) owns gates
// (p, p+2) of unit j. HALF-H SPLIT: each thread reads only h-half p (8 x
// ds_read_b128) and computes partials over that half for its own 2 gates AND
// its lane^1 partner's 2 gates; full dots recovered with two shfl_xor adds.
// xp is fp16: one dword per thread per step.
__global__ __launch_bounds__(256) void lstm_kernel(
    const _Float16* __restrict__ xp, // [T][B][512] thread-order, fp16
    const float* __restrict__ Whh,   // [512][128]
    const float* __restrict__ bhh,   // [512]
    const float* __restrict__ lnS, const float* __restrict__ lnB,  // [128]
    const float* __restrict__ fcW,   // [1][128]
    const float* __restrict__ fcb,   // [1]
    float*       __restrict__ out)   // [64]
{
    const int t  = threadIdx.x;      // 0..255
    const int b  = blockIdx.x;
    const int p  = t & 1;
    const int j  = t >> 1;           // hidden unit 0..127
    const int g0 = p * LH + j;            // own: type p   (i or f)
    const int g1 = (p + 2) * LH + j;      // own: type p+2 (g or o)
    const int q0 = (p ^ 1) * LH + j;      // partner's type
    const int q1 = ((p ^ 1) + 2) * LH + j;
    const int co = p * 64;                // this thread's h-half column offset

    // 4 half-rows of Whh (64 halfs each) -> 128 VGPRs total
    h2 wA[32], wB[32], wC[32], wD[32];
    {
        const float4* f0 = (const float4*)(Whh + (size_t)g0 * LH + co);
        const float4* f1 = (const float4*)(Whh + (size_t)g1 * LH + co);
        const float4* f2 = (const float4*)(Whh + (size_t)q0 * LH + co);
        const float4* f3 = (const float4*)(Whh + (size_t)q1 * LH + co);
        #pragma unroll
        for (int k4 = 0; k4 < 16; ++k4) {
            float4 v;
            v = f0[k4];
            { h2 a; a.x=(_Float16)v.x; a.y=(_Float16)v.y; wA[2*k4]=a;
              h2 c2; c2.x=(_Float16)v.z; c2.y=(_Float16)v.w; wA[2*k4+1]=c2; }
            v = f1[k4];
            { h2 a; a.x=(_Float16)v.x; a.y=(_Float16)v.y; wB[2*k4]=a;
              h2 c2; c2.x=(_Float16)v.z; c2.y=(_Float16)v.w; wB[2*k4+1]=c2; }
            v = f2[k4];
            { h2 a; a.x=(_Float16)v.x; a.y=(_Float16)v.y; wC[2*k4]=a;
              h2 c2; c2.x=(_Float16)v.z; c2.y=(_Float16)v.w; wC[2*k4+1]=c2; }
            v = f3[k4];
            { h2 a; a.x=(_Float16)v.x; a.y=(_Float16)v.y; wD[2*k4]=a;
              h2 c2; c2.x=(_Float16)v.z; c2.y=(_Float16)v.w; wD[2*k4+1]=c2; }
        }
    }
    const float bg0 = bhh[g0];
    const float bg1 = bhh[g1];
    const float s1_ = (p == 0) ? 2.f : 1.f;
    const float a1_ = (p == 0) ? 2.f : 1.f;
    const float d1_ = (p == 0) ? -1.f : 0.f;

    __shared__ _Float16 hb[2][LH];        // fp16 h, double buffered
    __shared__ float h_final[LH];
    if (t < 64) ((unsigned int*)&hb[0][0])[t] = 0u;
    float c = 0.f;
    float h_last = 0.f;
    __syncthreads();

    // t=0 xp slice (fp16 pair)
    h2 xh = as_h2(((const unsigned int*)(xp + (size_t)b * G4))[t]);
    float xvx = (float)xh.x, xvy = (float)xh.y;

    auto step = [&](const _Float16* hbR, _Float16* hbW, int ts) {
        const int tn = (ts + 1 < TT) ? ts + 1 : ts;
        const unsigned int un = ((const unsigned int*)(xp + ((size_t)tn * BB + b) * G4))[t];

        // read only this thread's h-half: 8 x ds_read_b128
        const uint4* hb4 = (const uint4*)(hbR + co);
        float sA0 = 0.f, sA1 = 0.f;
        float sB0 = 0.f, sB1 = 0.f;
        float sC0 = 0.f, sC1 = 0.f;
        float sD0 = 0.f, sD1 = 0.f;
        #pragma unroll
        for (int k = 0; k < 8; ++k) {
            uint4 u = hb4[k];
            h2 p0 = as_h2(u.x), p1 = as_h2(u.y), p2 = as_h2(u.z), p3 = as_h2(u.w);
            sA0 = fdot2_(p0, wA[4*k+0], sA0);
            sA1 = fdot2_(p1, wA[4*k+1], sA1);
            sA0 = fdot2_(p2, wA[4*k+2], sA0);
            sA1 = fdot2_(p3, wA[4*k+3], sA1);
            sB0 = fdot2_(p0, wB[4*k+0], sB0);
            sB1 = fdot2_(p1, wB[4*k+1], sB1);
            sB0 = fdot2_(p2, wB[4*k+2], sB0);
            sB1 = fdot2_(p3, wB[4*k+3], sB1);
            sC0 = fdot2_(p0, wC[4*k+0], sC0);
            sC1 = fdot2_(p1, wC[4*k+1], sC1);
            sC0 = fdot2_(p2, wC[4*k+2], sC0);
            sC1 = fdot2_(p3, wC[4*k+3], sC1);
            sD0 = fdot2_(p0, wD[4*k+0], sD0);
            sD1 = fdot2_(p1, wD[4*k+1], sD1);
            sD0 = fdot2_(p2, wD[4*k+2], sD0);
            sD1 = fdot2_(p3, wD[4*k+3], sD1);
        }
        const float sOwn0 = sA0 + sA1;
        const float sOwn1 = sB0 + sB1;
        const float sPar0 = sC0 + sC1;
        const float sPar1 = sD0 + sD1;
        const float gfull0 = sOwn0 + __shfl_xor(sPar0, 1) + bg0 + xvx;
        const float gfull1 = sOwn1 + __shfl_xor(sPar1, 1) + bg1 + xvy;

        float act0 = sigmoid_fast(gfull0);                                        // i or f
        float act1 = fmaf(a1_, __fdividef(1.f, 1.f + __expf(-s1_ * gfull1)), d1_); // g or o

        float o0 = __shfl_xor(act0, 1);
        float o1 = __shfl_xor(act1, 1);
        float iv = p ? o0 : act0;
        float fv = p ? act0 : o0;
        float gv = p ? o1 : act1;
        float ov = p ? act1 : o1;

        c = fmaf(fv, c, iv * gv);
        h_last = ov * tanh_fast(c);

        if (p == 0) hbW[j] = (_Float16)h_last;    // ds_write_b16, even lanes
        __syncthreads();

        h2 xn = as_h2(un);
        xvx = (float)xn.x; xvy = (float)xn.y;
    };

    for (int ts = 0; ts < TT; ts += 2) {
        step(&hb[0][0], &hb[1][0], ts);
        step(&hb[1][0], &hb[0][0], ts + 1);
    }

    if (p == 0) h_final[j] = h_last;
    __syncthreads();
    if (t < 64) {
        float h0 = h_final[t], h1 = h_final[t + 64];
        float s1 = h0 + h1, s2 = h0*h0 + h1*h1;
        #pragma unroll
        for (int off = 32; off >= 1; off >>= 1) {
            s1 += __shfl_xor(s1, off);
            s2 += __shfl_xor(s2, off);
        }
        float mu  = s1 * (1.f/128.f);
        float var = s2 * (1.f/128.f) - mu * mu;
        float rr  = rsqrtf(var + 1e-5f);
        float pv = ((h0 - mu)*rr*lnS[t]      + lnB[t])      * fcW[t]
                 + ((h1 - mu)*rr*lnS[t + 64] + lnB[t + 64]) * fcW[t + 64];
        #pragma unroll
        for (int off = 32; off >= 1; off >>= 1) pv += __shfl_xor(pv, off);
        if (t == 0) out[b] = pv + fcb[0];
    }
}

extern "C" void kernel_launch(void* const* d_in, const int* in_sizes, int n_in,
                              void* d_out, int out_size, void* d_ws, size_t ws_size,
                              hipStream_t stream) {
    const float* x     = (const float*)d_in[0];
    const float* ea    = (const float*)d_in[1];
    const float* xseq  = (const float*)d_in[2];
    const float* linW  = (const float*)d_in[3];
    const float* linB  = (const float*)d_in[4];
    const float* mW1   = (const float*)d_in[5];
    const float* mb1   = (const float*)d_in[6];
    const float* mW2   = (const float*)d_in[7];
    const float* mb2   = (const float*)d_in[8];
    const float* eps   = (const float*)d_in[9];
    const float* lnS   = (const float*)d_in[10];
    const float* lnB   = (const float*)d_in[11];
    const float* Wih   = (const float*)d_in[12];
    const float* Whh   = (const float*)d_in[13];
    const float* bih   = (const float*)d_in[14];
    const float* bhh   = (const float*)d_in[15];
    const float* llnS  = (const float*)d_in[16];
    const float* llnB  = (const float*)d_in[17];
    const float* fcW   = (const float*)d_in[18];
    const float* fcb   = (const float*)d_in[19];
    const int*   eidx  = (const int*)d_in[20];
    const int*   nidx  = (const int*)d_in[21];
    float* out = (float*)d_out;

    const int* srcs = eidx;
    const int* dsts = eidx + NE;

    // workspace layout
    float* ws   = (float*)d_ws;
    float* agg  = ws;                              // NN*64
    float* h1   = agg  + (size_t)NN * HID;
    float* h2m  = h1   + (size_t)NN * HID;
    float* selp = h2m  + (size_t)NN * HID;         // BB*G4
    float* W2T  = selp + (size_t)BB * G4;          // 32*G4
    _Float16* xpb = (_Float16*)(W2T + (size_t)32 * G4);  // TT*BB*G4 halfs
    int*   deg    = (int*)(xpb + (size_t)TT * BB * G4);  // NN
    int*   rowptr = deg + NN;                      // NN+1
    int*   head   = rowptr + NN + 2;               // NN
    int*   loc    = head + NN;                     // NN
    int*   bsum   = loc + NN;                      // SCB
    int*   boff   = bsum + SCB + 3;                // SCB
    int*   perm   = boff + SCB + 3;                // NE
    int*   ssrc   = perm + NE;                     // NE
    int*   sdst   = ssrc + NE;                     // NE
    uintptr_t ep = (uintptr_t)(sdst + NE);
    ep = (ep + 15) & ~(uintptr_t)15;
    _Float16* easort = (_Float16*)ep;              // NE*64 halfs = 102.4 MB
    _Float16* x16    = easort + (size_t)NE * HID;  // NN*64 halfs
    _Float16* h1_16  = x16 + (size_t)NN * HID;     // NN*64 halfs

    const size_t aggBytes = (size_t)NN * HID * sizeof(float);

    // ---- CSR build + dst-sorted fp16 edge table + x fp16 (shared by both layers) ----
    hipMemsetAsync(deg, 0, (size_t)NN * sizeof(int), stream);
    hist_cvtx_kernel<<<HBLK + XBLK, 256, 0, stream>>>(dsts, deg, x, x16);
    scan1_kernel<<<SCB, 512, 0, stream>>>(deg, loc, bsum);
    scan2_kernel<<<1, 1, 0, stream>>>(bsum, boff, rowptr);
    scan3_kernel<<<SCB, 512, 0, stream>>>(loc, boff, rowptr, head);
    scatter_kernel<<<(NE + 255) / 256, 256, 0, stream>>>(srcs, dsts, head, perm, ssrc, sdst);
    permute_zero_kernel<<<PBLK + ZBLK, 256, 0, stream>>>(ea, perm, (ushort4*)easort, agg);

    // ---- layer 0 ----
    edge_mfma_kernel<<<2048, 256, 0, stream>>>(x16, easort, linW, linB, ssrc, sdst, agg);
    node_kernel<<<512, 256, 0, stream>>>(x, agg, mW1, mb1, mW2, mb2, eps, lnS, lnB, h1, h1_16);
    // ---- layer 1 ----
    hipMemsetAsync(agg, 0, aggBytes, stream);
    edge_mfma_kernel<<<2048, 256, 0, stream>>>(h1_16, easort, linW + 64*64, linB + 64, ssrc, sdst, agg);
    node_kernel<<<512, 256, 0, stream>>>(h1, agg, mW1 + 64*64, mb1 + 64, mW2 + 64*64, mb2 + 64,
                                         eps + 1, lnS + 64, lnB + 64, h2m, (_Float16*)nullptr);
    // ---- LSTM input projection (permuted to lstm thread order, fp16) ----
    prep_kernel<<<BB + 1, 512, 0, stream>>>(Wih, bih, h2m, nidx, W2T, selp);
    xp_kernel<<<TT * BB, 512, 0, stream>>>(xseq, selp, W2T, xpb);
    // ---- LSTM recurrence + head (256 threads, half-h split) ----
    lstm_kernel<<<BB, 256, 0, stream>>>(xpb, Whh, bhh, llnS, llnB, fcW, fcb, out);
}